// Round 1
// 200.248 us; speedup vs baseline: 1.0053x; 1.0053x over previous
//
#include <hip/hip_runtime.h>

typedef unsigned short u16;
typedef unsigned int u32;

#define BATCH 2
#define TTEXT 2048
#define DIM 1024
#define TMED 8
#define MTOK 256
#define HEADS 16
#define DHEAD 64
#define INNER 1024
#define TM 2048            // TMED * MTOK
#define QSCALE 0.125f      // DHEAD^-0.5
#define QCHUNK 64          // queries per attention block

typedef __attribute__((ext_vector_type(8))) short bf16x8;
typedef __attribute__((ext_vector_type(4))) float f32x4;

__device__ __forceinline__ float b2f(u16 u){
  union { float f; u32 i; } x; x.i = ((u32)u) << 16; return x.f;
}
__device__ __forceinline__ u16 f2b(float f){
  union { float f; u32 i; } x; x.f = f;
  u32 r = x.i + 0x7FFFu + ((x.i >> 16) & 1u);   // RNE
  return (u16)(r >> 16);
}

#define GLDS16(g, l) __builtin_amdgcn_global_load_lds( \
    (const __attribute__((address_space(1))) u32*)(g), \
    (__attribute__((address_space(3))) u32*)(l), 16, 0, 0)

// ---------------- fused preprocessing: scan + LN + media cvt + W transpose ----------------
// All four stages are mutually independent; one launch replaces four serial ones.
// block 0            : cumsum(media_locations) -> tt
// blocks 1..4096     : LayerNorm row (bid-1)
// blocks 4097..8192  : media fp32->bf16, 1024 elems per block
// blocks 8193..12288 : W transpose tiles (z = (bid-8193)>>10)
__global__ __launch_bounds__(256) void prep_kernel(
    const unsigned char* __restrict__ raw, int* __restrict__ tt,
    const float* __restrict__ x, const float* __restrict__ gamma,
    const float* __restrict__ beta, u16* __restrict__ xn,
    const float* __restrict__ media, u16* __restrict__ medb,
    const float* __restrict__ Wq, const float* __restrict__ Wkv,
    const float* __restrict__ Wout, u16* __restrict__ Wqt,
    u16* __restrict__ Wkvt, u16* __restrict__ Woutt)
{
  __shared__ float smem[32 * 33];      // 4224 B, reused by every path
  int bid = blockIdx.x;
  int t = threadIdx.x;

  if (bid == 0){
    // ---- scan ----
    int* sd = (int*)smem;
    int c = 0;
    for (int i = t; i < 4096; i += 256) c += (raw[i] != 0);
    sd[t] = c; __syncthreads();
    for (int off = 128; off; off >>= 1){
      if (t < off) sd[t] += sd[t + off];
      __syncthreads();
    }
    int is_byte = (sd[0] >= 9);
    __syncthreads();
    const int* as_int = (const int*)raw;
    for (int b = 0; b < BATCH; b++){
      int inc[8]; int s = 0;
      #pragma unroll
      for (int k = 0; k < 8; k++){
        int i = b * TTEXT + t * 8 + k;
        int v = is_byte ? (raw[i] != 0) : (as_int[i] != 0);
        s += v; inc[k] = s;
      }
      sd[t] = s; __syncthreads();
      for (int off = 1; off < 256; off <<= 1){
        int v2 = (t >= off) ? sd[t - off] : 0;
        __syncthreads();
        sd[t] += v2;
        __syncthreads();
      }
      int excl = sd[t] - s;
      #pragma unroll
      for (int k = 0; k < 8; k++) tt[b * TTEXT + t * 8 + k] = excl + inc[k];
      __syncthreads();
    }
  } else if (bid <= 4096){
    // ---- LayerNorm ----
    int row = bid - 1;
    float* ps  = smem;
    float* pss = smem + 4;
    float4 v = *(const float4*)(x + (size_t)row * DIM + t * 4);
    float s  = v.x + v.y + v.z + v.w;
    float ss = v.x*v.x + v.y*v.y + v.z*v.z + v.w*v.w;
    #pragma unroll
    for (int off = 32; off; off >>= 1){ s += __shfl_xor(s, off); ss += __shfl_xor(ss, off); }
    int w = t >> 6;
    if ((t & 63) == 0){ ps[w] = s; pss[w] = ss; }
    __syncthreads();
    if (t == 0){
      float S = ps[0] + ps[1] + ps[2] + ps[3];
      float SS = pss[0] + pss[1] + pss[2] + pss[3];
      float mu = S * (1.f / DIM);
      float var = SS * (1.f / DIM) - mu * mu;
      smem[8] = mu; smem[9] = rsqrtf(var + 1e-5f);
    }
    __syncthreads();
    float mu = smem[8], rs = smem[9];
    float4 g  = *(const float4*)(gamma + t * 4);
    float4 be = *(const float4*)(beta + t * 4);
    ushort4 o;
    o.x = f2b((v.x - mu) * rs * g.x + be.x);
    o.y = f2b((v.y - mu) * rs * g.y + be.y);
    o.z = f2b((v.z - mu) * rs * g.z + be.z);
    o.w = f2b((v.w - mu) * rs * g.w + be.w);
    *(ushort4*)(xn + (size_t)row * DIM + t * 4) = o;
  } else if (bid <= 8192){
    // ---- media fp32 -> bf16 ----
    int i = (bid - 4097) * 1024 + t * 4;
    float4 v = *(const float4*)(media + i);
    ushort4 o;
    o.x = f2b(v.x); o.y = f2b(v.y); o.z = f2b(v.z); o.w = f2b(v.w);
    *(ushort4*)(medb + i) = o;
  } else {
    // ---- W transpose ----
    int tb = bid - 8193;
    int z = tb >> 10;
    int rem = tb & 1023;
    int by = rem >> 5;
    int bx = rem & 31;
    float (*tile)[33] = (float(*)[33])smem;
    const float* W; u16* Wt; int N;
    if (z == 0){ W = Wq;   Wt = Wqt;   N = 1024; }
    else if (z == 1){ W = Wout; Wt = Woutt; N = 1024; }
    else { W = Wkv; Wt = Wkvt; N = 2048; bx += (z - 2) * 32; }
    const int K = 1024;
    int tx = t & 31, ty = t >> 5;       // 32 x 8
    int n = bx * 32 + tx;
    #pragma unroll
    for (int i = 0; i < 32; i += 8)
      tile[ty + i][tx] = W[(size_t)(by * 32 + ty + i) * N + n];
    __syncthreads();
    int k2 = by * 32 + tx;
    #pragma unroll
    for (int i = 0; i < 32; i += 8)
      Wt[(size_t)(bx * 32 + ty + i) * K + k2] = f2b(tile[tx][ty + i]);
  }
}

// ---------------- MFMA GEMM body: C[M,N] = A[M,K] @ Bt[N,K]^T, bf16 in ----------------
// Double-buffered LDS, ONE barrier per K-step (2-phase). XCD-chunked block decode:
// each XCD (bid%8) owns a contiguous 4-block M-stripe across all N-blocks, so its
// L2 working set is A-stripe (1MB) + B (2-4MB) instead of all of A (8.4MB).
// MODE 0: bf16 C [M][N].  MODE 1: fp32 C [M][N].
// MODE 2: KV scatter bf16 -> K token-major [B,H,TM,64] (Cp), V dim-major [B,H,64,TM] (C2p).
// Fixed geometry: M=4096 (32 m-blocks, 4 per XCD), N/BN n-blocks.
template<int MODE, int BN>
__device__ __forceinline__ void gemm_body(u16* __restrict__ As, u16* __restrict__ Bs,
                                          int bid,
                                          const u16* __restrict__ A,
                                          const u16* __restrict__ Bt,
                                          void* __restrict__ Cp,
                                          u16* __restrict__ C2p,
                                          int N, int K){
  constexpr int BCOLS = BN / 32;         // 16-col tiles per wave in N
  int tid = threadIdx.x;
  int wave = tid >> 6, lane = tid & 63;

  int xcd = bid & 7, idx = bid >> 3;
  int mb = xcd * 4 + (idx & 3);
  int nb = idx >> 2;
  int m0 = mb * 128, n0 = nb * BN;

  int wm = (wave & 1) * 64, wn = (wave >> 1) * (BN / 2);
  int quad = lane >> 4, l16 = lane & 15;

  f32x4 acc[4][BCOLS];
  #pragma unroll
  for (int r = 0; r < 4; r++)
    #pragma unroll
    for (int c = 0; c < BCOLS; c++) acc[r][c] = (f32x4){0.f, 0.f, 0.f, 0.f};

  const u16* ag = A + (size_t)(m0 + wave * 32 + (lane >> 2)) * K + (lane & 3) * 8;
  const u16* bg;
  u16* asl0 = As + wave * 32 * 32;
  u16* bsl0;
  if (BN == 128){
    bg = Bt + (size_t)(n0 + wave * 32 + (lane >> 2)) * K + (lane & 3) * 8;
    bsl0 = Bs + wave * 32 * 32;
  } else {
    bg = Bt + (size_t)(n0 + wave * 16 + (lane >> 2)) * K + (lane & 3) * 8;
    bsl0 = Bs + wave * 16 * 32;
  }

  auto stage = [&](int k0, int buf){
    u16* asl = asl0 + buf * 128 * 32;
    u16* bsl = bsl0 + buf * BN * 32;
    GLDS16(ag + k0,                  asl);
    GLDS16(ag + k0 + 16 * (size_t)K, asl + 16 * 32);
    GLDS16(bg + k0,                  bsl);
    if (BN == 128) GLDS16(bg + k0 + 16 * (size_t)K, bsl + 16 * 32);
  };

  int steps = K >> 5;
  stage(0, 0);
  for (int s = 0; s < steps; s++){
    __syncthreads();                     // drains stage(s); frees buf[(s+1)&1] for overwrite
    if (s + 1 < steps) stage((s + 1) << 5, (s + 1) & 1);
    const u16* Ab = As + (s & 1) * 128 * 32;
    const u16* Bb = Bs + (s & 1) * BN * 32;
    bf16x8 af[4], bf[BCOLS];
    #pragma unroll
    for (int r = 0; r < 4; r++)
      af[r] = *(const bf16x8*)&Ab[(wm + r * 16 + l16) * 32 + quad * 8];
    #pragma unroll
    for (int c = 0; c < BCOLS; c++)
      bf[c] = *(const bf16x8*)&Bb[(wn + c * 16 + l16) * 32 + quad * 8];
    #pragma unroll
    for (int r = 0; r < 4; r++)
      #pragma unroll
      for (int c = 0; c < BCOLS; c++)
        acc[r][c] = __builtin_amdgcn_mfma_f32_16x16x32_bf16(af[r], bf[c], acc[r][c], 0, 0, 0);
  }

  #pragma unroll
  for (int r = 0; r < 4; r++){
    #pragma unroll
    for (int c = 0; c < BCOLS; c++){
      int rG = m0 + wm + r * 16 + quad * 4;      // + i
      int cG = n0 + wn + c * 16 + l16;
      if (MODE == 0){
        u16* C = (u16*)Cp;
        #pragma unroll
        for (int i = 0; i < 4; i++)
          C[(size_t)(rG + i) * N + cG] = f2b(acc[r][c][i]);
      } else if (MODE == 1){
        float* C = (float*)Cp;
        #pragma unroll
        for (int i = 0; i < 4; i++)
          C[(size_t)(rG + i) * N + cG] = acc[r][c][i];
      } else {
        int bb = rG >> 11, jj = rG & 2047;       // 4-row groups never cross batch
        if (cG < INNER){
          // K token-major: kB[((b*H+h)*TM + token)*64 + d]
          int hh = cG >> 6, dd = cG & 63;
          u16* kp = (u16*)Cp + (((size_t)bb * HEADS + hh) * TM + jj) * DHEAD + dd;
          #pragma unroll
          for (int i = 0; i < 4; i++)
            kp[(size_t)i * DHEAD] = f2b(acc[r][c][i]);
        } else {
          // V dim-major: vT[((b*H+h)*64 + d)*TM + token]
          int cc = cG - INNER;
          int hh = cc >> 6, dd = cc & 63;
          u16* vp = C2p + (((size_t)bb * HEADS + hh) * DHEAD + dd) * TM + jj;
          ushort4 o;
          o.x = f2b(acc[r][c][0]); o.y = f2b(acc[r][c][1]);
          o.z = f2b(acc[r][c][2]); o.w = f2b(acc[r][c][3]);
          *(ushort4*)vp = o;
        }
      }
    }
  }
}

// ---------------- fused Q-proj + KV-proj (independent GEMMs, one launch) ----------------
// bid < 512 : Q = xn @ Wqt^T   (MODE 0, BN=64,  4096x1024x1024)
// bid >= 512: KV = medb @ Wkvt^T scatter (MODE 2, BN=128, 4096x2048x1024)
// 512 % 8 == 0 so each half keeps a clean bid%8 -> XCD mapping.
__global__ __launch_bounds__(256) void qkv_kernel(const u16* __restrict__ xn,
                                                  const u16* __restrict__ Wqt,
                                                  u16* __restrict__ qb,
                                                  const u16* __restrict__ medb,
                                                  const u16* __restrict__ Wkvt,
                                                  u16* __restrict__ kB,
                                                  u16* __restrict__ vT){
  __shared__ u16 As[2 * 128 * 32];
  __shared__ u16 Bs[2 * 128 * 32];     // sized for BN=128; Q path uses half
  int bid = blockIdx.x;
  if (bid < 512)
    gemm_body<0, 64>(As, Bs, bid, xn, Wqt, qb, nullptr, 1024, 1024);
  else
    gemm_body<2, 128>(As, Bs, bid - 512, medb, Wkvt, kB, vT, 2048, 1024);
}

// ---------------- output projection ----------------
__global__ __launch_bounds__(256) void out_kernel(const u16* __restrict__ ao,
                                                  const u16* __restrict__ Woutt,
                                                  float* __restrict__ out){
  __shared__ u16 As[2 * 128 * 32];
  __shared__ u16 Bs[2 * 64 * 32];
  gemm_body<1, 64>(As, Bs, blockIdx.x, ao, Woutt, out, nullptr, 1024, 1024);
}

// ---------------- MFMA attention: 64 queries x 1 head per block ----------------
// (unchanged from the verified round-9 version: XCD swizzle + registered O select
//  + single coalesced write)
__global__ __launch_bounds__(256, 3) void attn_kernel(const u16* __restrict__ qb,
                                                      const u16* __restrict__ kB,
                                                      const u16* __restrict__ vT,
                                                      const int* __restrict__ tt,
                                                      u16* __restrict__ ao){
  __shared__ u16 KsP[128 * 72];        // K half [128 keys][72]; P half [64 q][136]; O strip [64 q][72]
  __shared__ u16 Vh[64 * 136];         // V half [64 d][128 keys pad->136]
  __shared__ int miq[QCHUNK];
  __shared__ int present[8];

  int t = threadIdx.x;
  int wave = t >> 6, lane = t & 63, quad = lane >> 4, l16 = lane & 15;
  int id = blockIdx.x;
  int pair = id & 31, chunk = id >> 5;  // XCD swizzle: id%8 == pair%8 fixed per (b,h)
  int b = pair >> 4, h = pair & 15;
  int q0 = chunk * QCHUNK;

  if (t < 8) present[t] = 0;
  __syncthreads();
  if (t < QCHUNK){
    int v = tt[b * TTEXT + q0 + t] - 1;
    miq[t] = v;
    if (v >= 0 && v < 8) present[v] = 1;
  }
  const u16* qrow = qb + (size_t)(b * TTEXT + q0 + wave * 16 + l16) * INNER
                       + h * DHEAD + quad * 8;
  bf16x8 aq0 = *(const bf16x8*)(qrow);
  bf16x8 aq1 = *(const bf16x8*)(qrow + 32);
  __syncthreads();                     // miq/present visible to all

  int myi[4];
  #pragma unroll
  for (int i = 0; i < 4; i++) myi[i] = miq[wave * 16 + quad * 4 + i];

  const size_t kvh = (size_t)b * HEADS + h;
  const u16* kg = kB + kvh * TM * DHEAD;            // [token][64]
  const u16* vg = vT + kvh * DHEAD * TM;            // [d][TM]

  f32x4 Osel[4];
  #pragma unroll
  for (int c4 = 0; c4 < 4; c4++) Osel[c4] = (f32x4){0.f, 0.f, 0.f, 0.f};

  for (int mi = 0; mi < 8; mi++){
    if (!present[mi]) continue;                     // block-uniform

    f32x4 S[16];
    #pragma unroll
    for (int c = 0; c < 16; c++) S[c] = (f32x4){0.f, 0.f, 0.f, 0.f};
    #pragma unroll
    for (int kh = 0; kh < 2; kh++){
      __syncthreads();   // prior KsP reads done (prev half QK / prev mi P)
      #pragma unroll
      for (int p = 0; p < 4; p++){
        int idx = p * 256 + t;
        int row = idx >> 3, seg = idx & 7;
        uint4 v = *(const uint4*)(kg + (size_t)(mi * MTOK + kh * 128 + row) * DHEAD + seg * 8);
        *(uint4*)(KsP + row * 72 + seg * 8) = v;
      }
      __syncthreads();
      #pragma unroll
      for (int ks = 0; ks < 2; ks++){
        bf16x8 aq = ks ? aq1 : aq0;
        #pragma unroll
        for (int c = 0; c < 8; c++){
          bf16x8 bk = *(const bf16x8*)&KsP[(c * 16 + l16) * 72 + ks * 32 + quad * 8];
          S[kh * 8 + c] = __builtin_amdgcn_mfma_f32_16x16x32_bf16(aq, bk, S[kh * 8 + c], 0, 0, 0);
        }
      }
    }

    float mx[4], sm[4];
    #pragma unroll
    for (int i = 0; i < 4; i++) mx[i] = -1e30f;
    #pragma unroll
    for (int c = 0; c < 16; c++)
      #pragma unroll
      for (int i = 0; i < 4; i++){
        float sv = S[c][i] * QSCALE; S[c][i] = sv; mx[i] = fmaxf(mx[i], sv);
      }
    #pragma unroll
    for (int off = 1; off < 16; off <<= 1)
      #pragma unroll
      for (int i = 0; i < 4; i++) mx[i] = fmaxf(mx[i], __shfl_xor(mx[i], off));
    #pragma unroll
    for (int i = 0; i < 4; i++) sm[i] = 0.f;
    #pragma unroll
    for (int c = 0; c < 16; c++)
      #pragma unroll
      for (int i = 0; i < 4; i++){
        float e = __expf(S[c][i] - mx[i]); S[c][i] = e; sm[i] += e;
      }
    #pragma unroll
    for (int off = 1; off < 16; off <<= 1)
      #pragma unroll
      for (int i = 0; i < 4; i++) sm[i] += __shfl_xor(sm[i], off);
    #pragma unroll
    for (int i = 0; i < 4; i++) sm[i] = 1.f / sm[i];

    f32x4 O[4];
    #pragma unroll
    for (int c4 = 0; c4 < 4; c4++) O[c4] = (f32x4){0.f, 0.f, 0.f, 0.f};
    #pragma unroll
    for (int kh = 0; kh < 2; kh++){
      __syncthreads();   // prior KsP/Vh reads done
      #pragma unroll
      for (int c = 0; c < 8; c++)
        #pragma unroll
        for (int i = 0; i < 4; i++)
          KsP[(wave * 16 + quad * 4 + i) * 136 + c * 16 + l16] = f2b(S[kh * 8 + c][i] * sm[i]);
      #pragma unroll
      for (int p = 0; p < 4; p++){
        int idx = p * 256 + t;
        int row = idx >> 4, seg = idx & 15;
        uint4 v = *(const uint4*)(vg + (size_t)row * TM + mi * MTOK + kh * 128 + seg * 8);
        *(uint4*)(Vh + row * 136 + seg * 8) = v;
      }
      __syncthreads();
      #pragma unroll
      for (int k0 = 0; k0 < 4; k0++){
        bf16x8 ap = *(const bf16x8*)&KsP[(wave * 16 + l16) * 136 + k0 * 32 + quad * 8];
        #pragma unroll
        for (int c4 = 0; c4 < 4; c4++){
          bf16x8 bv = *(const bf16x8*)&Vh[(c4 * 16 + l16) * 136 + k0 * 32 + quad * 8];
          O[c4] = __builtin_amdgcn_mfma_f32_16x16x32_bf16(ap, bv, O[c4], 0, 0, 0);
        }
      }
    }

    #pragma unroll
    for (int c4 = 0; c4 < 4; c4++)
      #pragma unroll
      for (int i = 0; i < 4; i++)
        Osel[c4][i] = (myi[i] == mi) ? O[c4][i] : Osel[c4][i];
  }

  // single coalesced O write via intra-wave LDS transpose (own strip, no barrier)
  #pragma unroll
  for (int c4 = 0; c4 < 4; c4++)
    #pragma unroll
    for (int i = 0; i < 4; i++)
      KsP[(wave * 16 + quad * 4 + i) * 72 + c4 * 16 + l16] = f2b(Osel[c4][i]);
  int r = lane >> 2, sidx = lane & 3;
  #pragma unroll
  for (int p = 0; p < 2; p++){
    int seg = p * 4 + sidx;
    uint4 v = *(const uint4*)&KsP[(wave * 16 + r) * 72 + seg * 8];
    *(uint4*)(ao + (size_t)(b * TTEXT + q0 + wave * 16 + r) * INNER + h * DHEAD + seg * 8) = v;
  }
}

extern "C" void kernel_launch(void* const* d_in, const int* in_sizes, int n_in,
                              void* d_out, int out_size, void* d_ws, size_t ws_size,
                              hipStream_t stream){
  const float* x      = (const float*)d_in[0];
  const float* media  = (const float*)d_in[1];
  const unsigned char* locs = (const unsigned char*)d_in[2];
  const float* gamma  = (const float*)d_in[3];
  const float* beta   = (const float*)d_in[4];
  const float* Wq     = (const float*)d_in[5];
  const float* Wkv    = (const float*)d_in[6];
  const float* Wout   = (const float*)d_in[7];

  // workspace layout (~58 MB), all bf16 intermediates
  char* ws = (char*)d_ws;
  int* tt    = (int*)ws;   ws += 16384;
  u16* xn    = (u16*)ws;   ws += (size_t)4096 * 1024 * 2;   // [B*T][DIM]
  u16* medb  = (u16*)ws;   ws += (size_t)4096 * 1024 * 2;   // [B*TM][DIM]
  u16* Wqt   = (u16*)ws;   ws += (size_t)1024 * 1024 * 2;   // [INNER][DIM]
  u16* Wkvt  = (u16*)ws;   ws += (size_t)2048 * 1024 * 2;   // [2*INNER][DIM]
  u16* Woutt = (u16*)ws;   ws += (size_t)1024 * 1024 * 2;   // [DIM][INNER]
  u16* qb    = (u16*)ws;   ws += (size_t)4096 * 1024 * 2;   // [B*T][INNER]
  u16* kB    = (u16*)ws;   ws += (size_t)4096 * 1024 * 2;   // [B,H,TM,64] token-major
  u16* vT    = (u16*)ws;   ws += (size_t)4096 * 1024 * 2;   // [B,H,64,TM] dim-major
  u16* ao    = (u16*)ws;   ws += (size_t)4096 * 1024 * 2;   // [B*T][INNER]

  prep_kernel<<<12289, 256, 0, stream>>>(locs, tt, x, gamma, beta, xn,
                                         media, medb, Wq, Wkv, Wout,
                                         Wqt, Wkvt, Woutt);
  qkv_kernel<<<1024, 256, 0, stream>>>(xn, Wqt, qb, medb, Wkvt, kB, vT);
  attn_kernel<<<1024, 256, 0, stream>>>(qb, kB, vT, tt, ao);
  out_kernel<<<512, 256, 0, stream>>>(ao, Woutt, (float*)d_out);
}

// Round 2
// 185.975 us; speedup vs baseline: 1.0824x; 1.0767x over previous
//
#include <hip/hip_runtime.h>

typedef unsigned short u16;
typedef unsigned int u32;

#define BATCH 2
#define TTEXT 2048
#define DIM 1024
#define TMED 8
#define MTOK 256
#define HEADS 16
#define DHEAD 64
#define INNER 1024
#define TM 2048            // TMED * MTOK
#define QSCALE 0.125f      // DHEAD^-0.5
#define QCHUNK 64          // queries per attention block

typedef __attribute__((ext_vector_type(8))) short bf16x8;
typedef __attribute__((ext_vector_type(4))) float f32x4;

__device__ __forceinline__ float b2f(u16 u){
  union { float f; u32 i; } x; x.i = ((u32)u) << 16; return x.f;
}
__device__ __forceinline__ u16 f2b(float f){
  union { float f; u32 i; } x; x.f = f;
  u32 r = x.i + 0x7FFFu + ((x.i >> 16) & 1u);   // RNE
  return (u16)(r >> 16);
}

#define GLDS16(g, l) __builtin_amdgcn_global_load_lds( \
    (const __attribute__((address_space(1))) u32*)(g), \
    (__attribute__((address_space(3))) u32*)(l), 16, 0, 0)

// ---------------- fused preprocessing: scan + LN + media cvt + W transpose ----------------
__global__ __launch_bounds__(256) void prep_kernel(
    const unsigned char* __restrict__ raw, int* __restrict__ tt,
    const float* __restrict__ x, const float* __restrict__ gamma,
    const float* __restrict__ beta, u16* __restrict__ xn,
    const float* __restrict__ media, u16* __restrict__ medb,
    const float* __restrict__ Wq, const float* __restrict__ Wkv,
    const float* __restrict__ Wout, u16* __restrict__ Wqt,
    u16* __restrict__ Wkvt, u16* __restrict__ Woutt)
{
  __shared__ float smem[32 * 33];      // 4224 B, reused by every path
  int bid = blockIdx.x;
  int t = threadIdx.x;

  if (bid == 0){
    // ---- scan ----
    int* sd = (int*)smem;
    int c = 0;
    for (int i = t; i < 4096; i += 256) c += (raw[i] != 0);
    sd[t] = c; __syncthreads();
    for (int off = 128; off; off >>= 1){
      if (t < off) sd[t] += sd[t + off];
      __syncthreads();
    }
    int is_byte = (sd[0] >= 9);
    __syncthreads();
    const int* as_int = (const int*)raw;
    for (int b = 0; b < BATCH; b++){
      int inc[8]; int s = 0;
      #pragma unroll
      for (int k = 0; k < 8; k++){
        int i = b * TTEXT + t * 8 + k;
        int v = is_byte ? (raw[i] != 0) : (as_int[i] != 0);
        s += v; inc[k] = s;
      }
      sd[t] = s; __syncthreads();
      for (int off = 1; off < 256; off <<= 1){
        int v2 = (t >= off) ? sd[t - off] : 0;
        __syncthreads();
        sd[t] += v2;
        __syncthreads();
      }
      int excl = sd[t] - s;
      #pragma unroll
      for (int k = 0; k < 8; k++) tt[b * TTEXT + t * 8 + k] = excl + inc[k];
      __syncthreads();
    }
  } else if (bid <= 4096){
    // ---- LayerNorm ----
    int row = bid - 1;
    float* ps  = smem;
    float* pss = smem + 4;
    float4 v = *(const float4*)(x + (size_t)row * DIM + t * 4);
    float s  = v.x + v.y + v.z + v.w;
    float ss = v.x*v.x + v.y*v.y + v.z*v.z + v.w*v.w;
    #pragma unroll
    for (int off = 32; off; off >>= 1){ s += __shfl_xor(s, off); ss += __shfl_xor(ss, off); }
    int w = t >> 6;
    if ((t & 63) == 0){ ps[w] = s; pss[w] = ss; }
    __syncthreads();
    if (t == 0){
      float S = ps[0] + ps[1] + ps[2] + ps[3];
      float SS = pss[0] + pss[1] + pss[2] + pss[3];
      float mu = S * (1.f / DIM);
      float var = SS * (1.f / DIM) - mu * mu;
      smem[8] = mu; smem[9] = rsqrtf(var + 1e-5f);
    }
    __syncthreads();
    float mu = smem[8], rs = smem[9];
    float4 g  = *(const float4*)(gamma + t * 4);
    float4 be = *(const float4*)(beta + t * 4);
    ushort4 o;
    o.x = f2b((v.x - mu) * rs * g.x + be.x);
    o.y = f2b((v.y - mu) * rs * g.y + be.y);
    o.z = f2b((v.z - mu) * rs * g.z + be.z);
    o.w = f2b((v.w - mu) * rs * g.w + be.w);
    *(ushort4*)(xn + (size_t)row * DIM + t * 4) = o;
  } else if (bid <= 8192){
    // ---- media fp32 -> bf16 ----
    int i = (bid - 4097) * 1024 + t * 4;
    float4 v = *(const float4*)(media + i);
    ushort4 o;
    o.x = f2b(v.x); o.y = f2b(v.y); o.z = f2b(v.z); o.w = f2b(v.w);
    *(ushort4*)(medb + i) = o;
  } else {
    // ---- W transpose ----
    int tb = bid - 8193;
    int z = tb >> 10;
    int rem = tb & 1023;
    int by = rem >> 5;
    int bx = rem & 31;
    float (*tile)[33] = (float(*)[33])smem;
    const float* W; u16* Wt; int N;
    if (z == 0){ W = Wq;   Wt = Wqt;   N = 1024; }
    else if (z == 1){ W = Wout; Wt = Woutt; N = 1024; }
    else { W = Wkv; Wt = Wkvt; N = 2048; bx += (z - 2) * 32; }
    const int K = 1024;
    int tx = t & 31, ty = t >> 5;       // 32 x 8
    int n = bx * 32 + tx;
    #pragma unroll
    for (int i = 0; i < 32; i += 8)
      tile[ty + i][tx] = W[(size_t)(by * 32 + ty + i) * N + n];
    __syncthreads();
    int k2 = by * 32 + tx;
    #pragma unroll
    for (int i = 0; i < 32; i += 8)
      Wt[(size_t)(bx * 32 + ty + i) * K + k2] = f2b(tile[tx][ty + i]);
  }
}

// ================= 256x256 deep-pipelined GEMM (counted-vmcnt + LDS swizzle) =================
// BM=BN=256, BK=64, 512 threads (8 waves, 2M x 4N), per-wave output 128x64.
// LDS: 2 buffers x (A 256x64 + B 256x64) bf16 = 128 KiB, 1 block/CU.
// Staging: 8 x global_load_lds(16B)/thread/K-tile, linear LDS dest; global SOURCE is
// pre-swizzled seg^=(row&7) so ds_read side can XOR the same key (rule: both-sides-or-neither).
// Pipeline: stage(t+1) issued, then s_waitcnt vmcnt(8) waits only stage(t) (counted, never
// drains the in-flight tile), raw s_barrier, compute. Two raw barriers per K-tile.
// MODE 0: bf16 C [M][N].  MODE 2: KV scatter (K token-major Cp, V dim-major C2p).
template<int MODE>
__device__ __forceinline__ void gemm256_body(u16* lds, int bid,
    const u16* __restrict__ A, const u16* __restrict__ Bt,
    void* __restrict__ Cp, u16* __restrict__ C2p, int N){
  const int K = 1024;
  const int NT = 16;                    // K / 64
  int tid = threadIdx.x;
  int wave = tid >> 6, lane = tid & 63;
  int quad = lane >> 4, l16 = lane & 15;

  // XCD-chunked decode on the sub-grid (sub-grid size % 8 == 0)
  int xcd = bid & 7, idx = bid >> 3;
  int mb = xcd * 2 + (idx & 1);
  int nb = idx >> 1;
  int m0 = mb * 256, n0 = nb * 256;

  int wm = (wave & 1) * 128, wn = (wave >> 1) * 64;

  f32x4 acc[8][4];
  #pragma unroll
  for (int i = 0; i < 8; i++)
    #pragma unroll
    for (int j = 0; j < 4; j++) acc[i][j] = (f32x4){0.f, 0.f, 0.f, 0.f};

  // staging source: thread covers (row = tid>>3 within 64-row round, seg = tid&7),
  // fetches global seg ^ (row&7)  ->  LDS(row, s) holds global(row, s ^ (row&7))
  int swc = (((tid & 7) ^ ((tid >> 3) & 7)) << 3);
  const u16* ags = A  + (size_t)(m0 + (tid >> 3)) * K + swc;
  const u16* bgs = Bt + (size_t)(n0 + (tid >> 3)) * K + swc;
  int wofs = wave << 9;                 // wave*512 elems within a 64-row round

  auto stage = [&](int t, int buf){
    const u16* ag = ags + t * 64;
    const u16* bg = bgs + t * 64;
    u16* al = lds + buf * 32768 + wofs;
    u16* bl = al + 16384;
    #pragma unroll
    for (int g = 0; g < 4; g++)
      GLDS16(ag + (size_t)g * 64 * K, al + g * 4096);
    #pragma unroll
    for (int g = 0; g < 4; g++)
      GLDS16(bg + (size_t)g * 64 * K, bl + g * 4096);
  };

  int sw = l16 & 7;                     // read-side swizzle key = row & 7

  stage(0, 0);
  for (int t = 0; t < NT; t++){
    __builtin_amdgcn_s_barrier();       // prev compute's LDS reads done block-wide
    if (t + 1 < NT){
      stage(t + 1, (t + 1) & 1);
      asm volatile("s_waitcnt vmcnt(8)" ::: "memory");   // waits exactly stage(t)
    } else {
      asm volatile("s_waitcnt vmcnt(0)" ::: "memory");
    }
    __builtin_amdgcn_s_barrier();       // everyone's stage(t) landed
    __builtin_amdgcn_sched_barrier(0);

    const u16* Ab = lds + (t & 1) * 32768;
    const u16* Bb = Ab + 16384;
    #pragma unroll
    for (int ks = 0; ks < 2; ks++){
      int sread = (((ks * 4 + quad) ^ sw) << 3);
      bf16x8 bf[4], af[8];
      #pragma unroll
      for (int j = 0; j < 4; j++)
        bf[j] = *(const bf16x8*)&Bb[(wn + j * 16 + l16) * 64 + sread];
      #pragma unroll
      for (int i = 0; i < 8; i++)
        af[i] = *(const bf16x8*)&Ab[(wm + i * 16 + l16) * 64 + sread];
      __builtin_amdgcn_s_setprio(1);
      #pragma unroll
      for (int i = 0; i < 8; i++)
        #pragma unroll
        for (int j = 0; j < 4; j++)
          acc[i][j] = __builtin_amdgcn_mfma_f32_16x16x32_bf16(af[i], bf[j], acc[i][j], 0, 0, 0);
      __builtin_amdgcn_s_setprio(0);
    }
  }

  #pragma unroll
  for (int i = 0; i < 8; i++){
    #pragma unroll
    for (int j = 0; j < 4; j++){
      int rG = m0 + wm + i * 16 + quad * 4;      // + ii
      int cG = n0 + wn + j * 16 + l16;
      if (MODE == 0){
        u16* C = (u16*)Cp;
        #pragma unroll
        for (int ii = 0; ii < 4; ii++)
          C[(size_t)(rG + ii) * N + cG] = f2b(acc[i][j][ii]);
      } else {
        int bb = rG >> 11, jj = rG & 2047;       // 4-row groups never cross batch
        if (cG < INNER){
          int hh = cG >> 6, dd = cG & 63;
          u16* kp = (u16*)Cp + (((size_t)bb * HEADS + hh) * TM + jj) * DHEAD + dd;
          #pragma unroll
          for (int ii = 0; ii < 4; ii++)
            kp[(size_t)ii * DHEAD] = f2b(acc[i][j][ii]);
        } else {
          int cc = cG - INNER;
          int hh = cc >> 6, dd = cc & 63;
          u16* vp = C2p + (((size_t)bb * HEADS + hh) * DHEAD + dd) * TM + jj;
          ushort4 o;
          o.x = f2b(acc[i][j][0]); o.y = f2b(acc[i][j][1]);
          o.z = f2b(acc[i][j][2]); o.w = f2b(acc[i][j][3]);
          *(ushort4*)vp = o;
        }
      }
    }
  }
}

// fused Q-proj (64 blocks) + KV-proj (128 blocks), 512 threads each
__global__ __launch_bounds__(512, 2) void qkv_kernel(const u16* __restrict__ xn,
                                                     const u16* __restrict__ Wqt,
                                                     u16* __restrict__ qb,
                                                     const u16* __restrict__ medb,
                                                     const u16* __restrict__ Wkvt,
                                                     u16* __restrict__ kB,
                                                     u16* __restrict__ vT){
  __shared__ u16 lds[2 * 2 * 16384];   // 128 KiB
  int bid = blockIdx.x;
  if (bid < 64)
    gemm256_body<0>(lds, bid, xn, Wqt, qb, nullptr, 1024);
  else
    gemm256_body<2>(lds, bid - 64, medb, Wkvt, kB, vT, 2048);
}

// ---------------- 2-phase MFMA GEMM body (kept for output projection) ----------------
template<int MODE, int BN>
__device__ __forceinline__ void gemm_body(u16* __restrict__ As, u16* __restrict__ Bs,
                                          int bid,
                                          const u16* __restrict__ A,
                                          const u16* __restrict__ Bt,
                                          void* __restrict__ Cp,
                                          u16* __restrict__ C2p,
                                          int N, int K){
  constexpr int BCOLS = BN / 32;
  int tid = threadIdx.x;
  int wave = tid >> 6, lane = tid & 63;

  int xcd = bid & 7, idx = bid >> 3;
  int mb = xcd * 4 + (idx & 3);
  int nb = idx >> 2;
  int m0 = mb * 128, n0 = nb * BN;

  int wm = (wave & 1) * 64, wn = (wave >> 1) * (BN / 2);
  int quad = lane >> 4, l16 = lane & 15;

  f32x4 acc[4][BCOLS];
  #pragma unroll
  for (int r = 0; r < 4; r++)
    #pragma unroll
    for (int c = 0; c < BCOLS; c++) acc[r][c] = (f32x4){0.f, 0.f, 0.f, 0.f};

  const u16* ag = A + (size_t)(m0 + wave * 32 + (lane >> 2)) * K + (lane & 3) * 8;
  const u16* bg;
  u16* asl0 = As + wave * 32 * 32;
  u16* bsl0;
  if (BN == 128){
    bg = Bt + (size_t)(n0 + wave * 32 + (lane >> 2)) * K + (lane & 3) * 8;
    bsl0 = Bs + wave * 32 * 32;
  } else {
    bg = Bt + (size_t)(n0 + wave * 16 + (lane >> 2)) * K + (lane & 3) * 8;
    bsl0 = Bs + wave * 16 * 32;
  }

  auto stage = [&](int k0, int buf){
    u16* asl = asl0 + buf * 128 * 32;
    u16* bsl = bsl0 + buf * BN * 32;
    GLDS16(ag + k0,                  asl);
    GLDS16(ag + k0 + 16 * (size_t)K, asl + 16 * 32);
    GLDS16(bg + k0,                  bsl);
    if (BN == 128) GLDS16(bg + k0 + 16 * (size_t)K, bsl + 16 * 32);
  };

  int steps = K >> 5;
  stage(0, 0);
  for (int s = 0; s < steps; s++){
    __syncthreads();
    if (s + 1 < steps) stage((s + 1) << 5, (s + 1) & 1);
    const u16* Ab = As + (s & 1) * 128 * 32;
    const u16* Bb = Bs + (s & 1) * BN * 32;
    bf16x8 af[4], bf[BCOLS];
    #pragma unroll
    for (int r = 0; r < 4; r++)
      af[r] = *(const bf16x8*)&Ab[(wm + r * 16 + l16) * 32 + quad * 8];
    #pragma unroll
    for (int c = 0; c < BCOLS; c++)
      bf[c] = *(const bf16x8*)&Bb[(wn + c * 16 + l16) * 32 + quad * 8];
    #pragma unroll
    for (int r = 0; r < 4; r++)
      #pragma unroll
      for (int c = 0; c < BCOLS; c++)
        acc[r][c] = __builtin_amdgcn_mfma_f32_16x16x32_bf16(af[r], bf[c], acc[r][c], 0, 0, 0);
  }

  #pragma unroll
  for (int r = 0; r < 4; r++){
    #pragma unroll
    for (int c = 0; c < BCOLS; c++){
      int rG = m0 + wm + r * 16 + quad * 4;
      int cG = n0 + wn + c * 16 + l16;
      if (MODE == 0){
        u16* C = (u16*)Cp;
        #pragma unroll
        for (int i = 0; i < 4; i++)
          C[(size_t)(rG + i) * N + cG] = f2b(acc[r][c][i]);
      } else if (MODE == 1){
        float* C = (float*)Cp;
        #pragma unroll
        for (int i = 0; i < 4; i++)
          C[(size_t)(rG + i) * N + cG] = acc[r][c][i];
      }
    }
  }
}

// ---------------- output projection (2-phase, 512 blocks, unchanged) ----------------
__global__ __launch_bounds__(256) void out_kernel(const u16* __restrict__ ao,
                                                  const u16* __restrict__ Woutt,
                                                  float* __restrict__ out){
  __shared__ u16 As[2 * 128 * 32];
  __shared__ u16 Bs[2 * 64 * 32];
  gemm_body<1, 64>(As, Bs, blockIdx.x, ao, Woutt, out, nullptr, 1024, 1024);
}

// ---------------- MFMA attention: 64 queries x 1 head per block (unchanged) ----------------
__global__ __launch_bounds__(256, 3) void attn_kernel(const u16* __restrict__ qb,
                                                      const u16* __restrict__ kB,
                                                      const u16* __restrict__ vT,
                                                      const int* __restrict__ tt,
                                                      u16* __restrict__ ao){
  __shared__ u16 KsP[128 * 72];
  __shared__ u16 Vh[64 * 136];
  __shared__ int miq[QCHUNK];
  __shared__ int present[8];

  int t = threadIdx.x;
  int wave = t >> 6, lane = t & 63, quad = lane >> 4, l16 = lane & 15;
  int id = blockIdx.x;
  int pair = id & 31, chunk = id >> 5;
  int b = pair >> 4, h = pair & 15;
  int q0 = chunk * QCHUNK;

  if (t < 8) present[t] = 0;
  __syncthreads();
  if (t < QCHUNK){
    int v = tt[b * TTEXT + q0 + t] - 1;
    miq[t] = v;
    if (v >= 0 && v < 8) present[v] = 1;
  }
  const u16* qrow = qb + (size_t)(b * TTEXT + q0 + wave * 16 + l16) * INNER
                       + h * DHEAD + quad * 8;
  bf16x8 aq0 = *(const bf16x8*)(qrow);
  bf16x8 aq1 = *(const bf16x8*)(qrow + 32);
  __syncthreads();

  int myi[4];
  #pragma unroll
  for (int i = 0; i < 4; i++) myi[i] = miq[wave * 16 + quad * 4 + i];

  const size_t kvh = (size_t)b * HEADS + h;
  const u16* kg = kB + kvh * TM * DHEAD;
  const u16* vg = vT + kvh * DHEAD * TM;

  f32x4 Osel[4];
  #pragma unroll
  for (int c4 = 0; c4 < 4; c4++) Osel[c4] = (f32x4){0.f, 0.f, 0.f, 0.f};

  for (int mi = 0; mi < 8; mi++){
    if (!present[mi]) continue;

    f32x4 S[16];
    #pragma unroll
    for (int c = 0; c < 16; c++) S[c] = (f32x4){0.f, 0.f, 0.f, 0.f};
    #pragma unroll
    for (int kh = 0; kh < 2; kh++){
      __syncthreads();
      #pragma unroll
      for (int p = 0; p < 4; p++){
        int idx = p * 256 + t;
        int row = idx >> 3, seg = idx & 7;
        uint4 v = *(const uint4*)(kg + (size_t)(mi * MTOK + kh * 128 + row) * DHEAD + seg * 8);
        *(uint4*)(KsP + row * 72 + seg * 8) = v;
      }
      __syncthreads();
      #pragma unroll
      for (int ks = 0; ks < 2; ks++){
        bf16x8 aq = ks ? aq1 : aq0;
        #pragma unroll
        for (int c = 0; c < 8; c++){
          bf16x8 bk = *(const bf16x8*)&KsP[(c * 16 + l16) * 72 + ks * 32 + quad * 8];
          S[kh * 8 + c] = __builtin_amdgcn_mfma_f32_16x16x32_bf16(aq, bk, S[kh * 8 + c], 0, 0, 0);
        }
      }
    }

    float mx[4], sm[4];
    #pragma unroll
    for (int i = 0; i < 4; i++) mx[i] = -1e30f;
    #pragma unroll
    for (int c = 0; c < 16; c++)
      #pragma unroll
      for (int i = 0; i < 4; i++){
        float sv = S[c][i] * QSCALE; S[c][i] = sv; mx[i] = fmaxf(mx[i], sv);
      }
    #pragma unroll
    for (int off = 1; off < 16; off <<= 1)
      #pragma unroll
      for (int i = 0; i < 4; i++) mx[i] = fmaxf(mx[i], __shfl_xor(mx[i], off));
    #pragma unroll
    for (int i = 0; i < 4; i++) sm[i] = 0.f;
    #pragma unroll
    for (int c = 0; c < 16; c++)
      #pragma unroll
      for (int i = 0; i < 4; i++){
        float e = __expf(S[c][i] - mx[i]); S[c][i] = e; sm[i] += e;
      }
    #pragma unroll
    for (int off = 1; off < 16; off <<= 1)
      #pragma unroll
      for (int i = 0; i < 4; i++) sm[i] += __shfl_xor(sm[i], off);
    #pragma unroll
    for (int i = 0; i < 4; i++) sm[i] = 1.f / sm[i];

    f32x4 O[4];
    #pragma unroll
    for (int c4 = 0; c4 < 4; c4++) O[c4] = (f32x4){0.f, 0.f, 0.f, 0.f};
    #pragma unroll
    for (int kh = 0; kh < 2; kh++){
      __syncthreads();
      #pragma unroll
      for (int c = 0; c < 8; c++)
        #pragma unroll
        for (int i = 0; i < 4; i++)
          KsP[(wave * 16 + quad * 4 + i) * 136 + c * 16 + l16] = f2b(S[kh * 8 + c][i] * sm[i]);
      #pragma unroll
      for (int p = 0; p < 4; p++){
        int idx = p * 256 + t;
        int row = idx >> 4, seg = idx & 15;
        uint4 v = *(const uint4*)(vg + (size_t)row * TM + mi * MTOK + kh * 128 + seg * 8);
        *(uint4*)(Vh + row * 136 + seg * 8) = v;
      }
      __syncthreads();
      #pragma unroll
      for (int k0 = 0; k0 < 4; k0++){
        bf16x8 ap = *(const bf16x8*)&KsP[(wave * 16 + l16) * 136 + k0 * 32 + quad * 8];
        #pragma unroll
        for (int c4 = 0; c4 < 4; c4++){
          bf16x8 bv = *(const bf16x8*)&Vh[(c4 * 16 + l16) * 136 + k0 * 32 + quad * 8];
          O[c4] = __builtin_amdgcn_mfma_f32_16x16x32_bf16(ap, bv, O[c4], 0, 0, 0);
        }
      }
    }

    #pragma unroll
    for (int c4 = 0; c4 < 4; c4++)
      #pragma unroll
      for (int i = 0; i < 4; i++)
        Osel[c4][i] = (myi[i] == mi) ? O[c4][i] : Osel[c4][i];
  }

  #pragma unroll
  for (int c4 = 0; c4 < 4; c4++)
    #pragma unroll
    for (int i = 0; i < 4; i++)
      KsP[(wave * 16 + quad * 4 + i) * 72 + c4 * 16 + l16] = f2b(Osel[c4][i]);
  int r = lane >> 2, sidx = lane & 3;
  #pragma unroll
  for (int p = 0; p < 2; p++){
    int seg = p * 4 + sidx;
    uint4 v = *(const uint4*)&KsP[(wave * 16 + r) * 72 + seg * 8];
    *(uint4*)(ao + (size_t)(b * TTEXT + q0 + wave * 16 + r) * INNER + h * DHEAD + seg * 8) = v;
  }
}

extern "C" void kernel_launch(void* const* d_in, const int* in_sizes, int n_in,
                              void* d_out, int out_size, void* d_ws, size_t ws_size,
                              hipStream_t stream){
  const float* x      = (const float*)d_in[0];
  const float* media  = (const float*)d_in[1];
  const unsigned char* locs = (const unsigned char*)d_in[2];
  const float* gamma  = (const float*)d_in[3];
  const float* beta   = (const float*)d_in[4];
  const float* Wq     = (const float*)d_in[5];
  const float* Wkv    = (const float*)d_in[6];
  const float* Wout   = (const float*)d_in[7];

  // workspace layout (~58 MB), all bf16 intermediates
  char* ws = (char*)d_ws;
  int* tt    = (int*)ws;   ws += 16384;
  u16* xn    = (u16*)ws;   ws += (size_t)4096 * 1024 * 2;   // [B*T][DIM]
  u16* medb  = (u16*)ws;   ws += (size_t)4096 * 1024 * 2;   // [B*TM][DIM]
  u16* Wqt   = (u16*)ws;   ws += (size_t)1024 * 1024 * 2;   // [INNER][DIM]
  u16* Wkvt  = (u16*)ws;   ws += (size_t)2048 * 1024 * 2;   // [2*INNER][DIM]
  u16* Woutt = (u16*)ws;   ws += (size_t)1024 * 1024 * 2;   // [DIM][INNER]
  u16* qb    = (u16*)ws;   ws += (size_t)4096 * 1024 * 2;   // [B*T][INNER]
  u16* kB    = (u16*)ws;   ws += (size_t)4096 * 1024 * 2;   // [B,H,TM,64] token-major
  u16* vT    = (u16*)ws;   ws += (size_t)4096 * 1024 * 2;   // [B,H,64,TM] dim-major
  u16* ao    = (u16*)ws;   ws += (size_t)4096 * 1024 * 2;   // [B*T][INNER]

  prep_kernel<<<12289, 256, 0, stream>>>(locs, tt, x, gamma, beta, xn,
                                         media, medb, Wq, Wkv, Wout,
                                         Wqt, Wkvt, Woutt);
  qkv_kernel<<<192, 512, 0, stream>>>(xn, Wqt, qb, medb, Wkvt, kB, vT);
  attn_kernel<<<dim3(1024), 256, 0, stream>>>(qb, kB, vT, tt, ao);
  out_kernel<<<512, 256, 0, stream>>>(ao, Woutt, (float*)d_out);
}

// Round 3
// 184.517 us; speedup vs baseline: 1.0910x; 1.0079x over previous
//
#include <hip/hip_runtime.h>

typedef unsigned short u16;
typedef unsigned int u32;

#define BATCH 2
#define TTEXT 2048
#define DIM 1024
#define TMED 8
#define MTOK 256
#define HEADS 16
#define DHEAD 64
#define INNER 1024
#define TM 2048            // TMED * MTOK
#define QSCALE 0.125f      // DHEAD^-0.5
#define QCHUNK 64          // queries per attention block

typedef __attribute__((ext_vector_type(8))) short bf16x8;
typedef __attribute__((ext_vector_type(4))) float f32x4;

__device__ __forceinline__ float b2f(u16 u){
  union { float f; u32 i; } x; x.i = ((u32)u) << 16; return x.f;
}
__device__ __forceinline__ u16 f2b(float f){
  union { float f; u32 i; } x; x.f = f;
  u32 r = x.i + 0x7FFFu + ((x.i >> 16) & 1u);   // RNE
  return (u16)(r >> 16);
}

#define GLDS16(g, l) __builtin_amdgcn_global_load_lds( \
    (const __attribute__((address_space(1))) u32*)(g), \
    (__attribute__((address_space(3))) u32*)(l), 16, 0, 0)

// ---------------- fused preprocessing: scan + LN + media cvt + W transpose ----------------
__global__ __launch_bounds__(256) void prep_kernel(
    const unsigned char* __restrict__ raw, int* __restrict__ tt,
    const float* __restrict__ x, const float* __restrict__ gamma,
    const float* __restrict__ beta, u16* __restrict__ xn,
    const float* __restrict__ media, u16* __restrict__ medb,
    const float* __restrict__ Wq, const float* __restrict__ Wkv,
    const float* __restrict__ Wout, u16* __restrict__ Wqt,
    u16* __restrict__ Wkvt, u16* __restrict__ Woutt)
{
  __shared__ float smem[32 * 33];      // 4224 B, reused by every path
  int bid = blockIdx.x;
  int t = threadIdx.x;

  if (bid == 0){
    // ---- scan ----
    int* sd = (int*)smem;
    int c = 0;
    for (int i = t; i < 4096; i += 256) c += (raw[i] != 0);
    sd[t] = c; __syncthreads();
    for (int off = 128; off; off >>= 1){
      if (t < off) sd[t] += sd[t + off];
      __syncthreads();
    }
    int is_byte = (sd[0] >= 9);
    __syncthreads();
    const int* as_int = (const int*)raw;
    for (int b = 0; b < BATCH; b++){
      int inc[8]; int s = 0;
      #pragma unroll
      for (int k = 0; k < 8; k++){
        int i = b * TTEXT + t * 8 + k;
        int v = is_byte ? (raw[i] != 0) : (as_int[i] != 0);
        s += v; inc[k] = s;
      }
      sd[t] = s; __syncthreads();
      for (int off = 1; off < 256; off <<= 1){
        int v2 = (t >= off) ? sd[t - off] : 0;
        __syncthreads();
        sd[t] += v2;
        __syncthreads();
      }
      int excl = sd[t] - s;
      #pragma unroll
      for (int k = 0; k < 8; k++) tt[b * TTEXT + t * 8 + k] = excl + inc[k];
      __syncthreads();
    }
  } else if (bid <= 4096){
    // ---- LayerNorm ----
    int row = bid - 1;
    float* ps  = smem;
    float* pss = smem + 4;
    float4 v = *(const float4*)(x + (size_t)row * DIM + t * 4);
    float s  = v.x + v.y + v.z + v.w;
    float ss = v.x*v.x + v.y*v.y + v.z*v.z + v.w*v.w;
    #pragma unroll
    for (int off = 32; off; off >>= 1){ s += __shfl_xor(s, off); ss += __shfl_xor(ss, off); }
    int w = t >> 6;
    if ((t & 63) == 0){ ps[w] = s; pss[w] = ss; }
    __syncthreads();
    if (t == 0){
      float S = ps[0] + ps[1] + ps[2] + ps[3];
      float SS = pss[0] + pss[1] + pss[2] + pss[3];
      float mu = S * (1.f / DIM);
      float var = SS * (1.f / DIM) - mu * mu;
      smem[8] = mu; smem[9] = rsqrtf(var + 1e-5f);
    }
    __syncthreads();
    float mu = smem[8], rs = smem[9];
    float4 g  = *(const float4*)(gamma + t * 4);
    float4 be = *(const float4*)(beta + t * 4);
    ushort4 o;
    o.x = f2b((v.x - mu) * rs * g.x + be.x);
    o.y = f2b((v.y - mu) * rs * g.y + be.y);
    o.z = f2b((v.z - mu) * rs * g.z + be.z);
    o.w = f2b((v.w - mu) * rs * g.w + be.w);
    *(ushort4*)(xn + (size_t)row * DIM + t * 4) = o;
  } else if (bid <= 8192){
    // ---- media fp32 -> bf16 ----
    int i = (bid - 4097) * 1024 + t * 4;
    float4 v = *(const float4*)(media + i);
    ushort4 o;
    o.x = f2b(v.x); o.y = f2b(v.y); o.z = f2b(v.z); o.w = f2b(v.w);
    *(ushort4*)(medb + i) = o;
  } else {
    // ---- W transpose ----
    int tb = bid - 8193;
    int z = tb >> 10;
    int rem = tb & 1023;
    int by = rem >> 5;
    int bx = rem & 31;
    float (*tile)[33] = (float(*)[33])smem;
    const float* W; u16* Wt; int N;
    if (z == 0){ W = Wq;   Wt = Wqt;   N = 1024; }
    else if (z == 1){ W = Wout; Wt = Woutt; N = 1024; }
    else { W = Wkv; Wt = Wkvt; N = 2048; bx += (z - 2) * 32; }
    const int K = 1024;
    int tx = t & 31, ty = t >> 5;       // 32 x 8
    int n = bx * 32 + tx;
    #pragma unroll
    for (int i = 0; i < 32; i += 8)
      tile[ty + i][tx] = W[(size_t)(by * 32 + ty + i) * N + n];
    __syncthreads();
    int k2 = by * 32 + tx;
    #pragma unroll
    for (int i = 0; i < 32; i += 8)
      Wt[(size_t)(bx * 32 + ty + i) * K + k2] = f2b(tile[tx][ty + i]);
  }
}

// ================= 256x256 8-phase GEMM (counted vmcnt, ks-half staging) =================
// BM=BN=256, BK=64 per K-tile, 512 threads (8 waves, 2M x 4N), per-wave out 128x64.
// LDS slots: A[2 buf][2 ks][256 rows][32 cols] bf16 (64 KiB) + B same = 128 KiB.
// Per K-tile: 4 phases (ks0/i-lo, ks0/i-hi, ks1/i-lo, ks1/i-hi), 16 MFMA each.
// Staging: 1 ks-half (A or B, 2 GLDS16/thread) per phase; vmcnt(8) every 2 phases
// keeps 4 half-tiles permanently in flight (never drains to 0; tails peeled).
// Ledger (steady state, tile t in buf c=t&1):
//   entry: outstanding {Aks1(t),Bks1(t),Aks0(t+1),Bks0(t+1),Aks1(t+1)?,..} <=12
//          vmcnt(8) drains Aks0(t),Bks0(t)  [needed by p0/p1]
//   p0: stage Aks1(t+1); p1: stage Bks1(t+1)
//   mid:   vmcnt(8) drains Aks1(t),Bks1(t)  [needed by p2/p3]
//   p2: stage Aks0(t+2); p3: stage Bks0(t+2)   [guard t+2<NT]
// Slot WAR safety: a slot's stage is always issued after the barrier that follows
// lgkmcnt(0)-completion of its previous reads (checked per slot).
// Col swizzle (both-sides, rule 21): stored seg s = (q + (row>>1))&3; staged from
// global seg ((lane&3)-(row>>1))&3; read at (q+(row>>1))&3 -> exactly 2-way (free).
// MODE 0: bf16 C [M][N].  MODE 2: KV scatter (K token-major Cp, V dim-major C2p).
template<int MODE>
__device__ __forceinline__ void gemm256_body(u16* lds, int bid,
    const u16* __restrict__ A, const u16* __restrict__ Bt,
    void* __restrict__ Cp, u16* __restrict__ C2p, int N){
  const int K = 1024;
  const int NT = 16;                    // K / 64
  int tid = threadIdx.x;
  int wave = tid >> 6, lane = tid & 63;
  int quad = lane >> 4, l16 = lane & 15;

  int xcd = bid & 7, idx = bid >> 3;
  int mb = xcd * 2 + (idx & 1);
  int nb = idx >> 1;
  int m0 = mb * 256, n0 = nb * 256;

  int wm = (wave & 1) * 128, wn = (wave >> 1) * 64;

  u16* ldsB = lds + 32768;

  f32x4 acc[8][4];
  #pragma unroll
  for (int i = 0; i < 8; i++)
    #pragma unroll
    for (int j = 0; j < 4; j++) acc[i][j] = (f32x4){0.f, 0.f, 0.f, 0.f};

  // ---- staging per-thread constants (2 GLDS chunks per half) ----
  const u16 *agp[2], *bgp[2];
  #pragma unroll
  for (int g = 0; g < 2; g++){
    int r = (wave * 2 + g) * 16 + (lane >> 2);            // tile-local row 0..255
    int gs = ((lane & 3) - ((r >> 1) & 3)) & 3;           // inverse col swizzle
    agp[g] = A  + (size_t)(m0 + r) * K + gs * 8;
    bgp[g] = Bt + (size_t)(n0 + r) * K + gs * 8;
  }

  auto stageA = [&](int u, int ks){
    u16* d = lds + (((u & 1) << 1) | ks) * 8192 + wave * 1024;
    #pragma unroll
    for (int g = 0; g < 2; g++)
      GLDS16(agp[g] + u * 64 + ks * 32, d + g * 512);
  };
  auto stageB = [&](int u, int ks){
    u16* d = ldsB + (((u & 1) << 1) | ks) * 8192 + wave * 1024;
    #pragma unroll
    for (int g = 0; g < 2; g++)
      GLDS16(bgp[g] + u * 64 + ks * 32, d + g * 512);
  };

  // ---- read-side offsets (elems within a [256][32] slot) ----
  int offA[8], offB[4];
  #pragma unroll
  for (int i = 0; i < 8; i++){
    int r = wm + i * 16 + l16;
    int s = (quad + ((r >> 1) & 3)) & 3;
    offA[i] = r * 32 + s * 8;
  }
  #pragma unroll
  for (int j = 0; j < 4; j++){
    int r = wn + j * 16 + l16;
    int s = (quad + ((r >> 1) & 3)) & 3;
    offB[j] = r * 32 + s * 8;
  }

  bf16x8 bf[4];
  auto phase = [&](const u16* Ah, const u16* Bh, int ihalf, bool loadB){
    if (loadB){
      #pragma unroll
      for (int j = 0; j < 4; j++) bf[j] = *(const bf16x8*)&Bh[offB[j]];
    }
    bf16x8 af[4];
    #pragma unroll
    for (int i = 0; i < 4; i++) af[i] = *(const bf16x8*)&Ah[offA[ihalf * 4 + i]];
    __builtin_amdgcn_s_barrier();
    asm volatile("s_waitcnt lgkmcnt(0)" ::: "memory");
    __builtin_amdgcn_sched_barrier(0);
    __builtin_amdgcn_s_setprio(1);
    #pragma unroll
    for (int i = 0; i < 4; i++)
      #pragma unroll
      for (int j = 0; j < 4; j++)
        acc[ihalf * 4 + i][j] =
          __builtin_amdgcn_mfma_f32_16x16x32_bf16(af[i], bf[j], acc[ihalf * 4 + i][j], 0, 0, 0);
    __builtin_amdgcn_s_setprio(0);
  };

  // ---- prologue: 6 halves, order defines the vmcnt ledger ----
  stageA(0, 0); stageB(0, 0);
  stageA(0, 1); stageB(0, 1);
  stageA(1, 0); stageB(1, 0);

  #pragma unroll 1
  for (int t = 0; t < NT - 1; t++){
    int c = t & 1;
    const u16* Ak0 = lds  + ((c << 1) | 0) * 8192;
    const u16* Bk0 = ldsB + ((c << 1) | 0) * 8192;
    const u16* Ak1 = lds  + ((c << 1) | 1) * 8192;
    const u16* Bk1 = ldsB + ((c << 1) | 1) * 8192;

    asm volatile("s_waitcnt vmcnt(8)" ::: "memory");
    __builtin_amdgcn_s_barrier();
    __builtin_amdgcn_sched_barrier(0);

    stageA(t + 1, 1);
    phase(Ak0, Bk0, 0, true);
    __builtin_amdgcn_s_barrier();
    __builtin_amdgcn_sched_barrier(0);

    stageB(t + 1, 1);
    phase(Ak0, Bk0, 1, false);

    asm volatile("s_waitcnt vmcnt(8)" ::: "memory");
    __builtin_amdgcn_s_barrier();
    __builtin_amdgcn_sched_barrier(0);

    if (t + 2 < NT) stageA(t + 2, 0);
    phase(Ak1, Bk1, 0, true);
    __builtin_amdgcn_s_barrier();
    __builtin_amdgcn_sched_barrier(0);

    if (t + 2 < NT) stageB(t + 2, 0);
    phase(Ak1, Bk1, 1, false);
  }

  // ---- peeled last tile (t = NT-1, buf 1) ----
  {
    const u16* Ak0 = lds  + ((1 << 1) | 0) * 8192;
    const u16* Bk0 = ldsB + ((1 << 1) | 0) * 8192;
    const u16* Ak1 = lds  + ((1 << 1) | 1) * 8192;
    const u16* Bk1 = ldsB + ((1 << 1) | 1) * 8192;

    asm volatile("s_waitcnt vmcnt(4)" ::: "memory");
    __builtin_amdgcn_s_barrier();
    __builtin_amdgcn_sched_barrier(0);
    phase(Ak0, Bk0, 0, true);
    __builtin_amdgcn_s_barrier();
    __builtin_amdgcn_sched_barrier(0);
    phase(Ak0, Bk0, 1, false);

    asm volatile("s_waitcnt vmcnt(0)" ::: "memory");
    __builtin_amdgcn_s_barrier();
    __builtin_amdgcn_sched_barrier(0);
    phase(Ak1, Bk1, 0, true);
    __builtin_amdgcn_s_barrier();
    __builtin_amdgcn_sched_barrier(0);
    phase(Ak1, Bk1, 1, false);
  }

  #pragma unroll
  for (int i = 0; i < 8; i++){
    #pragma unroll
    for (int j = 0; j < 4; j++){
      int rG = m0 + wm + i * 16 + quad * 4;      // + ii
      int cG = n0 + wn + j * 16 + l16;
      if (MODE == 0){
        u16* C = (u16*)Cp;
        #pragma unroll
        for (int ii = 0; ii < 4; ii++)
          C[(size_t)(rG + ii) * N + cG] = f2b(acc[i][j][ii]);
      } else {
        int bb = rG >> 11, jj = rG & 2047;       // 4-row groups never cross batch
        if (cG < INNER){
          int hh = cG >> 6, dd = cG & 63;
          u16* kp = (u16*)Cp + (((size_t)bb * HEADS + hh) * TM + jj) * DHEAD + dd;
          #pragma unroll
          for (int ii = 0; ii < 4; ii++)
            kp[(size_t)ii * DHEAD] = f2b(acc[i][j][ii]);
        } else {
          int cc = cG - INNER;
          int hh = cc >> 6, dd = cc & 63;
          u16* vp = C2p + (((size_t)bb * HEADS + hh) * DHEAD + dd) * TM + jj;
          ushort4 o;
          o.x = f2b(acc[i][j][0]); o.y = f2b(acc[i][j][1]);
          o.z = f2b(acc[i][j][2]); o.w = f2b(acc[i][j][3]);
          *(ushort4*)vp = o;
        }
      }
    }
  }
}

// fused Q-proj (64 blocks) + KV-proj (128 blocks), 512 threads each
__global__ __launch_bounds__(512, 1) void qkv_kernel(const u16* __restrict__ xn,
                                                     const u16* __restrict__ Wqt,
                                                     u16* __restrict__ qb,
                                                     const u16* __restrict__ medb,
                                                     const u16* __restrict__ Wkvt,
                                                     u16* __restrict__ kB,
                                                     u16* __restrict__ vT){
  __shared__ u16 lds[65536];           // 128 KiB
  int bid = blockIdx.x;
  if (bid < 64)
    gemm256_body<0>(lds, bid, xn, Wqt, qb, nullptr, 1024);
  else
    gemm256_body<2>(lds, bid - 64, medb, Wkvt, kB, vT, 2048);
}

// ---------------- 2-phase MFMA GEMM body (kept for output projection) ----------------
template<int MODE, int BN>
__device__ __forceinline__ void gemm_body(u16* __restrict__ As, u16* __restrict__ Bs,
                                          int bid,
                                          const u16* __restrict__ A,
                                          const u16* __restrict__ Bt,
                                          void* __restrict__ Cp,
                                          u16* __restrict__ C2p,
                                          int N, int K){
  constexpr int BCOLS = BN / 32;
  int tid = threadIdx.x;
  int wave = tid >> 6, lane = tid & 63;

  int xcd = bid & 7, idx = bid >> 3;
  int mb = xcd * 4 + (idx & 3);
  int nb = idx >> 2;
  int m0 = mb * 128, n0 = nb * BN;

  int wm = (wave & 1) * 64, wn = (wave >> 1) * (BN / 2);
  int quad = lane >> 4, l16 = lane & 15;

  f32x4 acc[4][BCOLS];
  #pragma unroll
  for (int r = 0; r < 4; r++)
    #pragma unroll
    for (int c = 0; c < BCOLS; c++) acc[r][c] = (f32x4){0.f, 0.f, 0.f, 0.f};

  const u16* ag = A + (size_t)(m0 + wave * 32 + (lane >> 2)) * K + (lane & 3) * 8;
  const u16* bg;
  u16* asl0 = As + wave * 32 * 32;
  u16* bsl0;
  if (BN == 128){
    bg = Bt + (size_t)(n0 + wave * 32 + (lane >> 2)) * K + (lane & 3) * 8;
    bsl0 = Bs + wave * 32 * 32;
  } else {
    bg = Bt + (size_t)(n0 + wave * 16 + (lane >> 2)) * K + (lane & 3) * 8;
    bsl0 = Bs + wave * 16 * 32;
  }

  auto stage = [&](int k0, int buf){
    u16* asl = asl0 + buf * 128 * 32;
    u16* bsl = bsl0 + buf * BN * 32;
    GLDS16(ag + k0,                  asl);
    GLDS16(ag + k0 + 16 * (size_t)K, asl + 16 * 32);
    GLDS16(bg + k0,                  bsl);
    if (BN == 128) GLDS16(bg + k0 + 16 * (size_t)K, bsl + 16 * 32);
  };

  int steps = K >> 5;
  stage(0, 0);
  for (int s = 0; s < steps; s++){
    __syncthreads();
    if (s + 1 < steps) stage((s + 1) << 5, (s + 1) & 1);
    const u16* Ab = As + (s & 1) * 128 * 32;
    const u16* Bb = Bs + (s & 1) * BN * 32;
    bf16x8 af[4], bf[BCOLS];
    #pragma unroll
    for (int r = 0; r < 4; r++)
      af[r] = *(const bf16x8*)&Ab[(wm + r * 16 + l16) * 32 + quad * 8];
    #pragma unroll
    for (int c = 0; c < BCOLS; c++)
      bf[c] = *(const bf16x8*)&Bb[(wn + c * 16 + l16) * 32 + quad * 8];
    #pragma unroll
    for (int r = 0; r < 4; r++)
      #pragma unroll
      for (int c = 0; c < BCOLS; c++)
        acc[r][c] = __builtin_amdgcn_mfma_f32_16x16x32_bf16(af[r], bf[c], acc[r][c], 0, 0, 0);
  }

  #pragma unroll
  for (int r = 0; r < 4; r++){
    #pragma unroll
    for (int c = 0; c < BCOLS; c++){
      int rG = m0 + wm + r * 16 + quad * 4;
      int cG = n0 + wn + c * 16 + l16;
      if (MODE == 0){
        u16* C = (u16*)Cp;
        #pragma unroll
        for (int i = 0; i < 4; i++)
          C[(size_t)(rG + i) * N + cG] = f2b(acc[r][c][i]);
      } else if (MODE == 1){
        float* C = (float*)Cp;
        #pragma unroll
        for (int i = 0; i < 4; i++)
          C[(size_t)(rG + i) * N + cG] = acc[r][c][i];
      }
    }
  }
}

// ---------------- output projection (2-phase, 512 blocks, unchanged) ----------------
__global__ __launch_bounds__(256) void out_kernel(const u16* __restrict__ ao,
                                                  const u16* __restrict__ Woutt,
                                                  float* __restrict__ out){
  __shared__ u16 As[2 * 128 * 32];
  __shared__ u16 Bs[2 * 64 * 32];
  gemm_body<1, 64>(As, Bs, blockIdx.x, ao, Woutt, out, nullptr, 1024, 1024);
}

// ---------------- MFMA attention: 64 queries x 1 head per block (unchanged) ----------------
__global__ __launch_bounds__(256, 3) void attn_kernel(const u16* __restrict__ qb,
                                                      const u16* __restrict__ kB,
                                                      const u16* __restrict__ vT,
                                                      const int* __restrict__ tt,
                                                      u16* __restrict__ ao){
  __shared__ u16 KsP[128 * 72];
  __shared__ u16 Vh[64 * 136];
  __shared__ int miq[QCHUNK];
  __shared__ int present[8];

  int t = threadIdx.x;
  int wave = t >> 6, lane = t & 63, quad = lane >> 4, l16 = lane & 15;
  int id = blockIdx.x;
  int pair = id & 31, chunk = id >> 5;
  int b = pair >> 4, h = pair & 15;
  int q0 = chunk * QCHUNK;

  if (t < 8) present[t] = 0;
  __syncthreads();
  if (t < QCHUNK){
    int v = tt[b * TTEXT + q0 + t] - 1;
    miq[t] = v;
    if (v >= 0 && v < 8) present[v] = 1;
  }
  const u16* qrow = qb + (size_t)(b * TTEXT + q0 + wave * 16 + l16) * INNER
                       + h * DHEAD + quad * 8;
  bf16x8 aq0 = *(const bf16x8*)(qrow);
  bf16x8 aq1 = *(const bf16x8*)(qrow + 32);
  __syncthreads();

  int myi[4];
  #pragma unroll
  for (int i = 0; i < 4; i++) myi[i] = miq[wave * 16 + quad * 4 + i];

  const size_t kvh = (size_t)b * HEADS + h;
  const u16* kg = kB + kvh * TM * DHEAD;
  const u16* vg = vT + kvh * DHEAD * TM;

  f32x4 Osel[4];
  #pragma unroll
  for (int c4 = 0; c4 < 4; c4++) Osel[c4] = (f32x4){0.f, 0.f, 0.f, 0.f};

  for (int mi = 0; mi < 8; mi++){
    if (!present[mi]) continue;

    f32x4 S[16];
    #pragma unroll
    for (int c = 0; c < 16; c++) S[c] = (f32x4){0.f, 0.f, 0.f, 0.f};
    #pragma unroll
    for (int kh = 0; kh < 2; kh++){
      __syncthreads();
      #pragma unroll
      for (int p = 0; p < 4; p++){
        int idx = p * 256 + t;
        int row = idx >> 3, seg = idx & 7;
        uint4 v = *(const uint4*)(kg + (size_t)(mi * MTOK + kh * 128 + row) * DHEAD + seg * 8);
        *(uint4*)(KsP + row * 72 + seg * 8) = v;
      }
      __syncthreads();
      #pragma unroll
      for (int ks = 0; ks < 2; ks++){
        bf16x8 aq = ks ? aq1 : aq0;
        #pragma unroll
        for (int c = 0; c < 8; c++){
          bf16x8 bk = *(const bf16x8*)&KsP[(c * 16 + l16) * 72 + ks * 32 + quad * 8];
          S[kh * 8 + c] = __builtin_amdgcn_mfma_f32_16x16x32_bf16(aq, bk, S[kh * 8 + c], 0, 0, 0);
        }
      }
    }

    float mx[4], sm[4];
    #pragma unroll
    for (int i = 0; i < 4; i++) mx[i] = -1e30f;
    #pragma unroll
    for (int c = 0; c < 16; c++)
      #pragma unroll
      for (int i = 0; i < 4; i++){
        float sv = S[c][i] * QSCALE; S[c][i] = sv; mx[i] = fmaxf(mx[i], sv);
      }
    #pragma unroll
    for (int off = 1; off < 16; off <<= 1)
      #pragma unroll
      for (int i = 0; i < 4; i++) mx[i] = fmaxf(mx[i], __shfl_xor(mx[i], off));
    #pragma unroll
    for (int i = 0; i < 4; i++) sm[i] = 0.f;
    #pragma unroll
    for (int c = 0; c < 16; c++)
      #pragma unroll
      for (int i = 0; i < 4; i++){
        float e = __expf(S[c][i] - mx[i]); S[c][i] = e; sm[i] += e;
      }
    #pragma unroll
    for (int off = 1; off < 16; off <<= 1)
      #pragma unroll
      for (int i = 0; i < 4; i++) sm[i] += __shfl_xor(sm[i], off);
    #pragma unroll
    for (int i = 0; i < 4; i++) sm[i] = 1.f / sm[i];

    f32x4 O[4];
    #pragma unroll
    for (int c4 = 0; c4 < 4; c4++) O[c4] = (f32x4){0.f, 0.f, 0.f, 0.f};
    #pragma unroll
    for (int kh = 0; kh < 2; kh++){
      __syncthreads();
      #pragma unroll
      for (int c = 0; c < 8; c++)
        #pragma unroll
        for (int i = 0; i < 4; i++)
          KsP[(wave * 16 + quad * 4 + i) * 136 + c * 16 + l16] = f2b(S[kh * 8 + c][i] * sm[i]);
      #pragma unroll
      for (int p = 0; p < 4; p++){
        int idx = p * 256 + t;
        int row = idx >> 4, seg = idx & 15;
        uint4 v = *(const uint4*)(vg + (size_t)row * TM + mi * MTOK + kh * 128 + seg * 8);
        *(uint4*)(Vh + row * 136 + seg * 8) = v;
      }
      __syncthreads();
      #pragma unroll
      for (int k0 = 0; k0 < 4; k0++){
        bf16x8 ap = *(const bf16x8*)&KsP[(wave * 16 + l16) * 136 + k0 * 32 + quad * 8];
        #pragma unroll
        for (int c4 = 0; c4 < 4; c4++){
          bf16x8 bv = *(const bf16x8*)&Vh[(c4 * 16 + l16) * 136 + k0 * 32 + quad * 8];
          O[c4] = __builtin_amdgcn_mfma_f32_16x16x32_bf16(ap, bv, O[c4], 0, 0, 0);
        }
      }
    }

    #pragma unroll
    for (int c4 = 0; c4 < 4; c4++)
      #pragma unroll
      for (int i = 0; i < 4; i++)
        Osel[c4][i] = (myi[i] == mi) ? O[c4][i] : Osel[c4][i];
  }

  #pragma unroll
  for (int c4 = 0; c4 < 4; c4++)
    #pragma unroll
    for (int i = 0; i < 4; i++)
      KsP[(wave * 16 + quad * 4 + i) * 72 + c4 * 16 + l16] = f2b(Osel[c4][i]);
  int r = lane >> 2, sidx = lane & 3;
  #pragma unroll
  for (int p = 0; p < 2; p++){
    int seg = p * 4 + sidx;
    uint4 v = *(const uint4*)&KsP[(wave * 16 + r) * 72 + seg * 8];
    *(uint4*)(ao + (size_t)(b * TTEXT + q0 + wave * 16 + r) * INNER + h * DHEAD + seg * 8) = v;
  }
}

extern "C" void kernel_launch(void* const* d_in, const int* in_sizes, int n_in,
                              void* d_out, int out_size, void* d_ws, size_t ws_size,
                              hipStream_t stream){
  const float* x      = (const float*)d_in[0];
  const float* media  = (const float*)d_in[1];
  const unsigned char* locs = (const unsigned char*)d_in[2];
  const float* gamma  = (const float*)d_in[3];
  const float* beta   = (const float*)d_in[4];
  const float* Wq     = (const float*)d_in[5];
  const float* Wkv    = (const float*)d_in[6];
  const float* Wout   = (const float*)d_in[7];

  // workspace layout (~58 MB), all bf16 intermediates
  char* ws = (char*)d_ws;
  int* tt    = (int*)ws;   ws += 16384;
  u16* xn    = (u16*)ws;   ws += (size_t)4096 * 1024 * 2;   // [B*T][DIM]
  u16* medb  = (u16*)ws;   ws += (size_t)4096 * 1024 * 2;   // [B*TM][DIM]
  u16* Wqt   = (u16*)ws;   ws += (size_t)1024 * 1024 * 2;   // [INNER][DIM]
  u16* Wkvt  = (u16*)ws;   ws += (size_t)2048 * 1024 * 2;   // [2*INNER][DIM]
  u16* Woutt = (u16*)ws;   ws += (size_t)1024 * 1024 * 2;   // [DIM][INNER]
  u16* qb    = (u16*)ws;   ws += (size_t)4096 * 1024 * 2;   // [B*T][INNER]
  u16* kB    = (u16*)ws;   ws += (size_t)4096 * 1024 * 2;   // [B,H,TM,64] token-major
  u16* vT    = (u16*)ws;   ws += (size_t)4096 * 1024 * 2;   // [B,H,64,TM] dim-major
  u16* ao    = (u16*)ws;   ws += (size_t)4096 * 1024 * 2;   // [B*T][INNER]

  prep_kernel<<<12289, 256, 0, stream>>>(locs, tt, x, gamma, beta, xn,
                                         media, medb, Wq, Wkv, Wout,
                                         Wqt, Wkvt, Woutt);
  qkv_kernel<<<192, 512, 0, stream>>>(xn, Wqt, qb, medb, Wkvt, kB, vT);
  attn_kernel<<<dim3(1024), 256, 0, stream>>>(qb, kB, vT, tt, ao);
  out_kernel<<<512, 256, 0, stream>>>(ao, Woutt, (float*)d_out);
}